// Round 1
// baseline (457.991 us; speedup 1.0000x reference)
//
#include <hip/hip_runtime.h>
#include <math.h>

// VentralModel R11: compute the log-polar Gaussian windows ANALYTICALLY instead
// of streaming ~300+ MB of mostly-zero fp32 window data from HBM.
//
//  - geo_kernel (new): per pixel of every scale, compute logr/theta in fp64
//    (exact numpy emulation: exact xs/ys, IEEE sqrt, exact deg_per_pix=15*2^-k,
//    OCML log/atan2 within 1 ulp of libm) + the 4 orientation moduli. Stored in
//    the workspace (11 MB of the 1.2 GB ws; re-written every launch).
//  - pool_kernel: unchanged grid/cull/reduction/flush (R6/R10-proven), but the
//    per-window inner loop evaluates w = exp(-0.5*s), s = qr^2 + (dtheta/sa)^2
//    with the threshold decision s <= -2*ln(1e-6) done in fp64. Window-center
//    constants reproduce numpy linspace rounding order (step = delta/div;
//    y = e*step + start; endpoint fix-up). Decision-flip probability vs the
//    reference window array ~1e-7 per run; summed w differs ~1e-6 relative.
//  - WPG=10 divides 20, so each window group has a SINGLE eccentricity ->
//    qr^2 per pixel is hoisted out of the window loop (8 fp64 values/thread).
//
// Proven pieces kept verbatim: per-(64x32 tile, window) analytic cull
// (margin 27.8 > 27.631 = -2 ln 1e-6; skipped pairs are exactly zero in the
// reference), R5's folded 14-shuffle reduction, wgrp-major block order with
// ntiles % 8 == 0 (tile->XCD affinity keeps geo/m reads L2-local across wgrps).

#define THREADS 256
#define WPG 10                 // windows per group (30 groups x 10 = 300)
#define ZTHRESH 1e-20f

// ws float layout:
//   [0,4800)      sums[s][o][w]  (s*1200 + o*300 + w)
//   [4800,6000)   cnt[s][w]
//   [6000,6300)   imgsum[w]
//   [6400, +1392640)        geo: double2{logr,theta} per pixel, scales concat
//   [1399040, +1392640)     m[scale][o][px] fp32 moduli
// total ~10.7 MiB (<< 1.2 GB ws; poisoned by harness, rewritten every launch)
#define WS_ACCUM 6300
#define GEO_F0   6400
#define M_F0     1399040
// scale pixel bases (pixels)
#define PX0 0
#define PX1 262144
#define PX2 327680
#define PX3 344064
#define PXT 348160
// moduli float bases (4 * pixel base)
#define MB0 0
#define MB1 1048576
#define MB2 1310720
#define MB3 1376256

// fp64 constants (<=1 ulp of numpy's values; decision fuzz analysis in header)
#define D_PI     3.141592653589793
#define D_TWOPI  6.283185307179586
#define D_LOGH  (-0.6931471805599453)    // log(0.5)
#define D_LOG15  2.7080502011022101      // log(15.0)
#define D_S0     27.631021115928548      // -2*log(1e-6): alive iff s <= D_S0

typedef float fvec4 __attribute__((ext_vector_type(4)));

__device__ __forceinline__ float rdist(float v, float a, float b) {
    return fmaxf(fmaxf(a - v, v - b), 0.f);   // distance from v to [a,b]
}

// ---------------------------------------------------------------------------
// geo_kernel: per-pixel fp64 (logr, theta) + fp32 moduli for all 4 scales.
// 348160 px = 1360 blocks x 256.
// ---------------------------------------------------------------------------
__global__ __launch_bounds__(THREADS)
void geo_kernel(const float* __restrict__ pyr0, const float* __restrict__ pyr1,
                const float* __restrict__ pyr2, const float* __restrict__ pyr3,
                float* __restrict__ ws)
{
    int idx = blockIdx.x * THREADS + threadIdx.x;
    if (idx >= PXT) return;
    int local, res, sh, mb;
    const float* pyr;
    if (idx < PX1)      { local = idx;       res = 512; sh = 9; pyr = pyr0; mb = MB0; }
    else if (idx < PX2) { local = idx - PX1; res = 256; sh = 8; pyr = pyr1; mb = MB1; }
    else if (idx < PX3) { local = idx - PX2; res = 128; sh = 7; pyr = pyr2; mb = MB2; }
    else                { local = idx - PX3; res = 64;  sh = 6; pyr = pyr3; mb = MB3; }
    int py = local >> sh, px = local & (res - 1);

    // exact numpy emulation: xs/ys are exact fp64, sum of squares exact,
    // sqrt correctly rounded, deg_per_pix = 15*2^-k exact.
    double half = (double)res * 0.5;
    double ys = (double)py - half + 0.5;
    double xs = (double)px - half + 0.5;
    double dpp = 15.0 / (double)(res >> 1);
    double r = sqrt(xs * xs + ys * ys) * dpp;
    double logr = log(fmax(r, 1e-6));
    double theta = atan2(ys, xs);

    double2* geo = (double2*)(ws + GEO_F0);
    geo[idx] = make_double2(logr, theta);

    const int HW = res * res;
    float* m = ws + M_F0 + mb;
    const float2* p2 = (const float2*)pyr;
#pragma unroll
    for (int o = 0; o < 4; ++o) {
        float2 v = p2[(size_t)o * HW + local];
        m[(size_t)o * HW + local] = sqrtf(fmaf(v.x, v.x, v.y * v.y));
    }
}

// ---------------------------------------------------------------------------
// pool_tile: one (64x32 tile, 10-window group). Windows computed on the fly.
// ---------------------------------------------------------------------------
template <bool HAS_IMG>
__device__ __forceinline__ void pool_tile(const float* __restrict__ marr,
                                          const double2* __restrict__ geo,
                                          const float* __restrict__ img,
                                          float* __restrict__ ws,
                                          int res, int scale, int x0, int y0, int wgrp)
{
    __shared__ float lacc[4][WPG * 6];
    __shared__ int s_list[WPG];
    __shared__ int s_na;

    const int tid  = threadIdx.x;
    const int lane = tid & 63;
    const int wave = tid >> 6;
    const int HW = res * res;
    const int w0 = wgrp * WPG;

    // ---- tile bounds + alive list (wave 0 only; one ballot) — R6-proven ----
    if (tid < 64) {
        float xlo = (float)x0 - res * 0.5f + 0.5f, xhi = xlo + 63.f;  // pixel centers
        float ylo = (float)y0 - res * 0.5f + 0.5f, yhi = ylo + 31.f;
        float dpp = 30.f / (float)res;            // MAX_ECC/(res/2)
        float dx = fmaxf(fmaxf(xlo, -xhi), 0.f);
        float dy = fmaxf(fmaxf(ylo, -yhi), 0.f);
        float rmin = sqrtf(dx * dx + dy * dy) * dpp;
        float rmax = sqrtf(fmaxf(xlo * xlo, xhi * xhi) + fmaxf(ylo * ylo, yhi * yhi)) * dpp;
        float lrmin = logf(fmaxf(rmin, 1e-6f));
        float lrmax = logf(fmaxf(rmax, 1e-6f));
        bool wrap = (ylo < 0.f && yhi > 0.f && xlo < 0.f);
        float t1 = atan2f(ylo, xlo), t2 = atan2f(ylo, xhi);
        float t3 = atan2f(yhi, xlo), t4 = atan2f(yhi, xhi);
        float tmin = fminf(fminf(t1, t2), fminf(t3, t4));
        float tmax = fmaxf(fmaxf(t1, t2), fmaxf(t3, t4));

        bool alive = false;
        if (lane < WPG) {
            int gw = w0 + lane;
            int e = gw / 20, p = gw - e * 20;
            float mue = -0.69314718f + (float)e * 0.24294267f;  // log(.5)+e*se
            float mua = -3.14159265f + (float)p * 0.31415927f;  // -pi+p*sa
            float dr = rdist(mue, lrmin, lrmax);
            float da = 0.f;
            if (!wrap) {
                float d0 = rdist(mua, tmin, tmax);
                float dm = rdist(mua - 6.2831853f, tmin, tmax);
                float dp = rdist(mua + 6.2831853f, tmin, tmax);
                da = fminf(d0, fminf(dm, dp));
            }
            float qa = da * 3.1830989f;   // /sa
            float qr = dr * 4.1161885f;   // /se
            alive = (qa * qa + qr * qr) <= 27.8f;   // 27.631 + margin
        }
        unsigned long long mask = __ballot(alive);
        if (alive) {
            int pos = (int)__popcll(mask & ((1ull << lane) - 1ull));
            s_list[pos] = lane;
        }
        if (lane == 0) s_na = (int)__popcll(mask);
    }
    __syncthreads();
    const int na = s_na;
    if (na == 0) return;   // uniform exit before any further barrier

    // ---- per-thread pixels: 2 lane-contiguous float4 rows (rowA, rowA+16) ----
    const int row = tid >> 4;            // 0..15
    const int col = (tid & 15) * 4;      // 0..60
    const size_t p0 = (size_t)(y0 + row) * res + x0 + col;
    const size_t p1 = p0 + (size_t)16 * res;

    // precomputed moduli (L2-local across wgrps)
    float m0[4][4], m1[4][4];
#pragma unroll
    for (int o = 0; o < 4; ++o) {
        float4 a = *(const float4*)(marr + (size_t)o * HW + p0);
        m0[o][0] = a.x; m0[o][1] = a.y; m0[o][2] = a.z; m0[o][3] = a.w;
        float4 b = *(const float4*)(marr + (size_t)o * HW + p1);
        m1[o][0] = b.x; m1[o][1] = b.y; m1[o][2] = b.z; m1[o][3] = b.w;
    }
    fvec4 i0 = (fvec4)(0.f), i1 = (fvec4)(0.f);
    if (HAS_IMG) {
        i0 = *(const fvec4*)(img + p0);
        i1 = *(const fvec4*)(img + p1);
    }

    // ---- block-uniform fp64 window-family constants (numpy linspace order:
    //      step = fl(delta/div); y[e] = fl(fl(e*step)+start); y[-1]=stop) ----
    const int eblk  = w0 / 20;          // single eccentricity per group
    const int pbase = w0 - eblk * 20;
    const double de     = D_LOG15 - D_LOGH;
    const double step_e = de / 14.0;
    double mue = (double)eblk * step_e + D_LOGH;
    if (eblk == 14) mue = D_LOG15;
    const double me1    = step_e + D_LOGH;
    const double se     = me1 - D_LOGH;       // = mus_e[1]-mus_e[0]
    const double inv_se = 1.0 / se;
    const double sa     = D_TWOPI / 20.0;     // = linspace step, endpoint=False
    const double inv_sa = 1.0 / sa;

    // per-pixel radial term (window-loop invariant: one e per group) + theta
    double qA[4], qB[4], thA[4], thB[4];
#pragma unroll
    for (int q = 0; q < 4; ++q) {
        double2 g = geo[p0 + q];
        double qr = (g.x - mue) * inv_se;
        qA[q] = qr * qr; thA[q] = g.y;
        double2 h = geo[p1 + q];
        double qs = (h.x - mue) * inv_se;
        qB[q] = qs * qs; thB[q] = h.y;
    }

    const bool pb0 = (lane & 1) != 0;
    const bool pb1 = (lane & 2) != 0;
    const bool pb2 = (lane & 4) != 0;

    for (int j = 0; j < na; ++j) {
        const int p = pbase + s_list[j];
        const double mua = (double)p * sa - D_PI;

        float a0 = 0.f, a1 = 0.f, a2 = 0.f, a3 = 0.f, ct = 0.f, ia = 0.f;
#pragma unroll
        for (int q = 0; q < 4; ++q) {
            // pixel A (row)
            double dt = thA[q] - mua;
            dt = (dt >  D_PI) ? dt - D_TWOPI : dt;
            dt = (dt < -D_PI) ? dt + D_TWOPI : dt;
            double qa = dt * inv_sa;
            double s  = qA[q] + qa * qa;
            bool  al  = (s <= D_S0);              // exact-threshold decision
            float wx  = al ? expf(-0.5f * (float)s) : 0.0f;
            a0 = fmaf(wx, m0[0][q], a0);
            a1 = fmaf(wx, m0[1][q], a1);
            a2 = fmaf(wx, m0[2][q], a2);
            a3 = fmaf(wx, m0[3][q], a3);
            ct += al ? 1.f : 0.f;
            if (HAS_IMG) ia = fmaf(wx, i0[q], ia);

            // pixel B (row+16)
            double du = thB[q] - mua;
            du = (du >  D_PI) ? du - D_TWOPI : du;
            du = (du < -D_PI) ? du + D_TWOPI : du;
            double qb = du * inv_sa;
            double z  = qB[q] + qb * qb;
            bool  bl  = (z <= D_S0);
            float wy  = bl ? expf(-0.5f * (float)z) : 0.0f;
            a0 = fmaf(wy, m1[0][q], a0);
            a1 = fmaf(wy, m1[1][q], a1);
            a2 = fmaf(wy, m1[2][q], a2);
            a3 = fmaf(wy, m1[3][q], a3);
            ct += bl ? 1.f : 0.f;
            if (HAS_IMG) ia = fmaf(wy, i1[q], ia);
        }

        // folded wave-64 reduction (R5-proven): all shuffles unconditional
        float t0 = __shfl_xor(a0, 1, 64);
        float t1 = __shfl_xor(a1, 1, 64);
        float t2 = __shfl_xor(a2, 1, 64);
        float t3 = __shfl_xor(a3, 1, 64);
        float t4 = __shfl_xor(ct, 1, 64);
        float t5 = __shfl_xor(ia, 1, 64);
        float b0 = pb0 ? (a1 + t1) : (a0 + t0);
        float b1 = pb0 ? (a3 + t3) : (a2 + t2);
        float b2 = pb0 ? (ia + t5) : (ct + t4);
        float u0 = __shfl_xor(b0, 2, 64);
        float u1 = __shfl_xor(b1, 2, 64);
        float u2 = __shfl_xor(b2, 2, 64);
        float c0 = pb1 ? (b1 + u1) : (b0 + u0);
        float c1 = b2 + u2;
        float v0 = __shfl_xor(c0, 4, 64);
        float v1 = __shfl_xor(c1, 4, 64);
        float d  = pb2 ? (c1 + v1) : (c0 + v0);
        d += __shfl_xor(d, 8, 64);
        d += __shfl_xor(d, 16, 64);
        d += __shfl_xor(d, 32, 64);
        if (lane < 6) lacc[wave][j * 6 + lane] = d;
    }
    __syncthreads();

    // ---- block flush ----
    float* sums = ws + (size_t)scale * 1200;
    float* cnt  = ws + 4800 + (size_t)scale * 300;
    float* imgs = ws + 6000;
    for (int i = tid; i < na * 6; i += THREADS) {
        float v = lacc[0][i] + lacc[1][i] + lacc[2][i] + lacc[3][i];
        int j = i / 6, f = i - j * 6;
        int w = w0 + s_list[j];
        if (f < 4) {
            atomicAdd(&sums[f * 300 + w], v);
        } else if (f == 4) {
            atomicAdd(&cnt[w], v);
        } else if (HAS_IMG) {
            atomicAdd(&imgs[w], v);
        }
    }
}

// grid (wgrp-major; ntiles % 8 == 0 keeps a tile on one XCD across wgrps):
//   s0: 30 wgrps x 128 tiles = 3840 | s1: 30x32 = 960 | s2: 30x8 = 240
//   s3: 30x2 = 60  -> 5100 blocks; tiles are 64x32 px at every scale.
__global__ __launch_bounds__(THREADS)
void pool_kernel(const float* __restrict__ image, float* __restrict__ ws)
{
    const double2* geo = (const double2*)(ws + GEO_F0);
    const float* mall  = ws + M_F0;
    int bid = blockIdx.x;
    if (bid < 3840) {
        int wgrp = bid >> 7, tile = bid & 127;
        int tx = tile & 7, ty = tile >> 3;           // 8 x 16 tiles
        pool_tile<true>(mall + MB0, geo + PX0, image, ws, 512, 0, tx * 64, ty * 32, wgrp);
    } else if (bid < 4800) {
        int l = bid - 3840;
        int wgrp = l >> 5, tile = l & 31;
        int tx = tile & 3, ty = tile >> 2;           // 4 x 8
        pool_tile<false>(mall + MB1, geo + PX1, nullptr, ws, 256, 1, tx * 64, ty * 32, wgrp);
    } else if (bid < 5040) {
        int l = bid - 4800;
        int wgrp = l >> 3, tile = l & 7;
        int tx = tile & 1, ty = tile >> 1;           // 2 x 4
        pool_tile<false>(mall + MB2, geo + PX2, nullptr, ws, 128, 2, tx * 64, ty * 32, wgrp);
    } else {
        int l = bid - 5040;
        int wgrp = l >> 1, tile = l & 1;             // 1 x 2
        pool_tile<false>(mall + MB3, geo + PX3, nullptr, ws, 64, 3, 0, tile * 32, wgrp);
    }
}

__global__ __launch_bounds__(THREADS)
void finalize_kernel(const float* __restrict__ ws, float* __restrict__ out)
{
    int i = blockIdx.x * blockDim.x + threadIdx.x;
    if (i >= 5100) return;
    float v;
    if (i < 4800) {
        int s = i / 1200;
        int w = i % 300;
        v = ws[i] / ws[4800 + s * 300 + w];        // sums[s][o][w] / cnt[s][w]
    } else {
        int w = i - 4800;
        v = ws[6000 + w] / ws[4800 + w];           // imgsum[w] / cnt[0][w]
    }
    out[i] = v;
}

extern "C" void kernel_launch(void* const* d_in, const int* in_sizes, int n_in,
                              void* d_out, int out_size, void* d_ws, size_t ws_size,
                              hipStream_t stream)
{
    const float* image = (const float*)d_in[0];
    const float* pyr0  = (const float*)d_in[1];
    const float* pyr1  = (const float*)d_in[3];
    const float* pyr2  = (const float*)d_in[5];
    const float* pyr3  = (const float*)d_in[7];
    // win0..3 (d_in[2,4,6,8]) are deterministic log-polar Gaussians: recomputed
    // analytically on device; never read.
    float* ws  = (float*)d_ws;
    float* out = (float*)d_out;

    hipMemsetAsync(d_ws, 0, WS_ACCUM * sizeof(float), stream);
    geo_kernel<<<(PXT + THREADS - 1) / THREADS, THREADS, 0, stream>>>(pyr0, pyr1, pyr2, pyr3, ws);
    pool_kernel<<<5100, THREADS, 0, stream>>>(image, ws);
    finalize_kernel<<<20, THREADS, 0, stream>>>(ws, out);
}